// Round 9
// baseline (2666.035 us; speedup 1.0000x reference)
//
#include <hip/hip_runtime.h>
#include <hip/hip_cooperative_groups.h>
#include <math.h>

namespace cg = cooperative_groups;

#define N_NODES 100000
#define N_EDGES 1200000
#define DIM 64
#define TDIM 32
#define NLAYERS 3
#define NGRAPH 500
#define NP (N_NODES + 1)

#define BUCKW 512
#define NBUCK ((N_NODES + BUCKW - 1) / BUCKW)   // 196
#define ECHUNK ((N_EDGES + 255) / 256)          // 4688
#define MLPBL ((N_NODES + 63) / 64)             // 1563

typedef unsigned short bfu;
typedef __attribute__((ext_vector_type(8))) short short8;
typedef __attribute__((ext_vector_type(4))) float v4f;

__device__ __forceinline__ float bf2f(bfu u) {
    union { unsigned int i; float f; } v; v.i = ((unsigned int)u) << 16; return v.f;
}
__device__ __forceinline__ float bflo(unsigned int d) {
    union { unsigned int i; float f; } v; v.i = d << 16; return v.f;
}
__device__ __forceinline__ float bfhi(unsigned int d) {
    union { unsigned int i; float f; } v; v.i = d & 0xFFFF0000u; return v.f;
}
__device__ __forceinline__ bfu f2bf(float f) {
    union { float f; unsigned int i; } v; v.f = f;
    unsigned int r = v.i + 0x7FFFu + ((v.i >> 16) & 1u);   // RNE
    return (bfu)(r >> 16);
}
__device__ __forceinline__ void accum8(float* acc, uint4 d) {
    acc[0] += bflo(d.x); acc[1] += bfhi(d.x);
    acc[2] += bflo(d.y); acc[3] += bfhi(d.y);
    acc[4] += bflo(d.z); acc[5] += bfhi(d.z);
    acc[6] += bflo(d.w); acc[7] += bfhi(d.w);
}

// ---------------- merged setup ----------------
__global__ __launch_bounds__(256) void k_setup(const float* __restrict__ x, bfu* __restrict__ xb,
                                               const int* __restrict__ gid, int* __restrict__ gstart,
                                               float* __restrict__ inv_safe, float* __restrict__ ncnt,
                                               const float* __restrict__ w1, const float* __restrict__ w2,
                                               const float* __restrict__ q1, const float* __restrict__ q2,
                                               bfu* __restrict__ w1t, bfu* __restrict__ w2t,
                                               bfu* __restrict__ q1t, bfu* __restrict__ q2t,
                                               const int* __restrict__ dst, int* __restrict__ bcnt) {
    int b = blockIdx.x, t = threadIdx.x;
    if (b < 6250) {
        int base = (b * 256 + t) * 4;
        float4 v = *(const float4*)&x[base];
        ushort4 o;
        o.x = f2bf(v.x); o.y = f2bf(v.y); o.z = f2bf(v.z); o.w = f2bf(v.w);
        *(ushort4*)&xb[base] = o;
    } else if (b == 6250) {
        for (int tt = t; tt <= NGRAPH; tt += 256) {
            int lo = 0, hi = N_NODES;
            while (lo < hi) {
                int mid = (lo + hi) >> 1;
                if (gid[mid] < tt) lo = mid + 1; else hi = mid;
            }
            gstart[tt] = lo;
        }
        __syncthreads();
        for (int tt = t; tt < NGRAPH; tt += 256) {
            int c = gstart[tt + 1] - gstart[tt];
            inv_safe[tt] = 1.0f / (float)(c > 1 ? c : 1);
            ncnt[tt] = (float)c;
        }
    } else if (b < 6299) {
        int i = (b - 6251) * 256 + t;     // 0..12287
        int l = i >> 12, k = (i >> 6) & 63, n = i & 63;
        int o = (l << 12) | (n << 6) | k;
        w1t[o] = f2bf(w1[i]);
        w2t[o] = f2bf(w2[i]);
        q1t[o] = f2bf(q1[i]);
        if (i < NLAYERS * 2048) {
            int l2 = i >> 11, rem = i & 2047, k2 = rem >> 5, n2 = rem & 31;
            q2t[l2 * 2048 + n2 * 64 + k2] = f2bf(q2[i]);
        }
    } else {
        __shared__ int h[NBUCK];
        for (int i = t; i < NBUCK; i += 256) h[i] = 0;
        __syncthreads();
        int e0 = (b - 6299) * ECHUNK;
        int e1 = e0 + ECHUNK; if (e1 > N_EDGES) e1 = N_EDGES;
        for (int e = e0 + t; e < e1; e += 256) atomicAdd(&h[dst[e] >> 9], 1);
        __syncthreads();
        for (int i = t; i < NBUCK; i += 256) if (h[i]) atomicAdd(&bcnt[i], h[i]);
    }
}

// ---------------- setup: bucket scan ----------------
__global__ __launch_bounds__(256) void k_bscan(const int* __restrict__ bcnt,
                                               int* __restrict__ bbase, int* __restrict__ bcursor,
                                               const int* __restrict__ gstart,
                                               const float* __restrict__ pb2all, float* __restrict__ out) {
    __shared__ int s[256];
    int t = threadIdx.x;
    s[t] = (t < NBUCK) ? bcnt[t] : 0;
    __syncthreads();
    for (int off = 1; off < 256; off <<= 1) {
        int v = (t >= off) ? s[t - off] : 0;
        __syncthreads();
        s[t] += v;
        __syncthreads();
    }
    int ex = t ? s[t - 1] : 0;
    if (t < NBUCK) { bbase[t] = ex; bcursor[t] = ex; }
    if (t == 0) bbase[NBUCK] = N_EDGES;
    for (int g = t; g < NGRAPH; g += 256) {
        int nn = gstart[g + 1] - gstart[g];
        for (int r = 0; r < NLAYERS * TDIM; r++)
            out[g * (NLAYERS * TDIM) + r] = (nn > 0) ? pb2all[r] : 0.f;
    }
}

__global__ __launch_bounds__(256) void k_bscatter(const int* __restrict__ src, const int* __restrict__ dst,
                                                  int* __restrict__ bcursor, int2* __restrict__ ebuf) {
    __shared__ int cnt[NBUCK];
    __shared__ int base[NBUCK];
    int t = threadIdx.x;
    for (int i = t; i < NBUCK; i += 256) cnt[i] = 0;
    __syncthreads();
    int e0 = blockIdx.x * ECHUNK;
    int e1 = e0 + ECHUNK; if (e1 > N_EDGES) e1 = N_EDGES;
    for (int e = e0 + t; e < e1; e += 256) atomicAdd(&cnt[dst[e] >> 9], 1);
    __syncthreads();
    for (int i = t; i < NBUCK; i += 256) base[i] = cnt[i] ? atomicAdd(&bcursor[i], cnt[i]) : 0;
    __syncthreads();
    for (int i = t; i < NBUCK; i += 256) cnt[i] = 0;
    __syncthreads();
    for (int e = e0 + t; e < e1; e += 256) {
        int d = dst[e];
        int b = d >> 9;
        int r = atomicAdd(&cnt[b], 1);
        ebuf[base[b] + r] = make_int2(src[e], d);
    }
}

__global__ __launch_bounds__(256) void k_bcsr(const int2* __restrict__ ebuf, const int* __restrict__ bbase,
                                              int* __restrict__ offs, int* __restrict__ csr) {
    __shared__ int ldeg[BUCKW];
    __shared__ int lscan[BUCKW];
    __shared__ int lcur[BUCKW];
    int t = threadIdx.x;
    int b = blockIdx.x;
    int nbase = b << 9;
    int ebeg = bbase[b], eend = bbase[b + 1];
    ldeg[t] = 0; ldeg[t + 256] = 0;
    __syncthreads();
    for (int e = ebeg + t; e < eend; e += 256) atomicAdd(&ldeg[ebuf[e].y - nbase], 1);
    __syncthreads();
    lscan[t] = ldeg[t]; lscan[t + 256] = ldeg[t + 256];
    __syncthreads();
    for (int off = 1; off < BUCKW; off <<= 1) {
        int i0 = t, i1 = t + 256;
        int v0 = (i0 >= off) ? lscan[i0 - off] : 0;
        int v1 = (i1 >= off) ? lscan[i1 - off] : 0;
        __syncthreads();
        lscan[i0] += v0; lscan[i1] += v1;
        __syncthreads();
    }
    int ex0 = lscan[t] - ldeg[t];
    int ex1 = lscan[t + 256] - ldeg[t + 256];
    lcur[t] = ex0; lcur[t + 256] = ex1;
    int n0 = nbase + t, n1 = nbase + t + 256;
    if (n0 < N_NODES) offs[n0] = ebeg + ex0;
    if (n1 < N_NODES) offs[n1] = ebeg + ex1;
    if (b == 0 && t == 0) offs[N_NODES] = N_EDGES;
    __syncthreads();
    for (int e = ebeg + t; e < eend; e += 256) {
        int2 p = ebuf[e];
        int slot = atomicAdd(&lcur[p.y - nbase], 1);
        csr[ebeg + slot] = p.x;
    }
}

// ================= FALLBACK PATH (r7-verified kernels, unchanged) =================
__global__ __launch_bounds__(256) void k_mlp(const bfu* __restrict__ feat, const int* __restrict__ offs,
                                             const int* __restrict__ csr, const float* __restrict__ eps, int l,
                                             const bfu* __restrict__ w1t, const float* __restrict__ b1,
                                             const bfu* __restrict__ w2t, const float* __restrict__ b2,
                                             const int* __restrict__ gid, bfu* __restrict__ hout,
                                             float* __restrict__ gsum, float* __restrict__ gsq) {
    __shared__ bfu hstage[64 * 80];
    __shared__ bfu ldsT[4][16 * 80];
    __shared__ int sG[4][16];
    int t = threadIdx.x;
    int w = t >> 6, lane = t & 63, m = lane & 15, q = lane >> 4;
    int nbase = blockIdx.x * 64 + w * 16;
    if (lane < 16) sG[w][lane] = (nbase + lane < N_NODES) ? gid[nbase + lane] : -1;

    {
        int nl = t >> 2;
        int c  = t & 3;
        int coff = c * 16;
        int node = blockIdx.x * 64 + nl;
        float ep = 1.0f + eps[l];
        float acc[16];
#pragma unroll
        for (int j = 0; j < 16; j++) acc[j] = 0.f;
        if (node < N_NODES) {
            int e0 = offs[node], e1 = offs[node + 1];
            if (e0 < e1) {
                int eL = e1 - 1;
                int sa = csr[e0];
                int sb = csr[(e0 + 1) < eL ? (e0 + 1) : eL];
                int sc = csr[(e0 + 2) < eL ? (e0 + 2) : eL];
                int sd = csr[(e0 + 3) < eL ? (e0 + 3) : eL];
                for (int e = e0; e < e1; e += 4) {
                    int en = e + 4;
                    int na = csr[en < eL ? en : eL];
                    int nb = csr[(en + 1) < eL ? (en + 1) : eL];
                    int nc = csr[(en + 2) < eL ? (en + 2) : eL];
                    int nd = csr[(en + 3) < eL ? (en + 3) : eL];
                    uint4 va0 = *(const uint4*)&feat[sa * DIM + coff];
                    uint4 va1 = *(const uint4*)&feat[sa * DIM + coff + 8];
                    uint4 vb0 = *(const uint4*)&feat[sb * DIM + coff];
                    uint4 vb1 = *(const uint4*)&feat[sb * DIM + coff + 8];
                    uint4 vc0 = *(const uint4*)&feat[sc * DIM + coff];
                    uint4 vc1 = *(const uint4*)&feat[sc * DIM + coff + 8];
                    uint4 vd0 = *(const uint4*)&feat[sd * DIM + coff];
                    uint4 vd1 = *(const uint4*)&feat[sd * DIM + coff + 8];
                    if (e + 1 >= e1) { vb0 = make_uint4(0u,0u,0u,0u); vb1 = make_uint4(0u,0u,0u,0u); }
                    if (e + 2 >= e1) { vc0 = make_uint4(0u,0u,0u,0u); vc1 = make_uint4(0u,0u,0u,0u); }
                    if (e + 3 >= e1) { vd0 = make_uint4(0u,0u,0u,0u); vd1 = make_uint4(0u,0u,0u,0u); }
                    accum8(acc, va0); accum8(acc + 8, va1);
                    accum8(acc, vb0); accum8(acc + 8, vb1);
                    accum8(acc, vc0); accum8(acc + 8, vc1);
                    accum8(acc, vd0); accum8(acc + 8, vd1);
                    sa = na; sb = nb; sc = nc; sd = nd;
                }
            }
            uint4 s0 = *(const uint4*)&feat[node * DIM + coff];
            uint4 s1 = *(const uint4*)&feat[node * DIM + coff + 8];
            acc[0] += ep * bflo(s0.x); acc[1] += ep * bfhi(s0.x);
            acc[2] += ep * bflo(s0.y); acc[3] += ep * bfhi(s0.y);
            acc[4] += ep * bflo(s0.z); acc[5] += ep * bfhi(s0.z);
            acc[6] += ep * bflo(s0.w); acc[7] += ep * bfhi(s0.w);
            acc[8]  += ep * bflo(s1.x); acc[9]  += ep * bfhi(s1.x);
            acc[10] += ep * bflo(s1.y); acc[11] += ep * bfhi(s1.y);
            acc[12] += ep * bflo(s1.z); acc[13] += ep * bfhi(s1.z);
            acc[14] += ep * bflo(s1.w); acc[15] += ep * bfhi(s1.w);
        }
        uint4 o0, o1;
        o0.x = ((unsigned int)f2bf(acc[1])  << 16) | f2bf(acc[0]);
        o0.y = ((unsigned int)f2bf(acc[3])  << 16) | f2bf(acc[2]);
        o0.z = ((unsigned int)f2bf(acc[5])  << 16) | f2bf(acc[4]);
        o0.w = ((unsigned int)f2bf(acc[7])  << 16) | f2bf(acc[6]);
        o1.x = ((unsigned int)f2bf(acc[9])  << 16) | f2bf(acc[8]);
        o1.y = ((unsigned int)f2bf(acc[11]) << 16) | f2bf(acc[10]);
        o1.z = ((unsigned int)f2bf(acc[13]) << 16) | f2bf(acc[12]);
        o1.w = ((unsigned int)f2bf(acc[15]) << 16) | f2bf(acc[14]);
        *(uint4*)&hstage[nl * 80 + coff] = o0;
        *(uint4*)&hstage[nl * 80 + coff + 8] = o1;
    }

    short8 a0 = *(const short8*)&hstage[(w * 16 + m) * 80 + q * 8];
    short8 a1 = *(const short8*)&hstage[(w * 16 + m) * 80 + 32 + q * 8];

    short8 bf1[4][2], bf2[4][2];
#pragma unroll
    for (int ct = 0; ct < 4; ct++)
#pragma unroll
        for (int kk = 0; kk < 2; kk++) {
            bf1[ct][kk] = *(const short8*)&w1t[(ct * 16 + m) * 64 + kk * 32 + q * 8];
            bf2[ct][kk] = *(const short8*)&w2t[(ct * 16 + m) * 64 + kk * 32 + q * 8];
        }

    bfu* my = ldsT[w];
#pragma unroll
    for (int ct = 0; ct < 4; ct++) {
        float bv = b1[ct * 16 + m];
        v4f acc = {bv, bv, bv, bv};
        acc = __builtin_amdgcn_mfma_f32_16x16x32_bf16(a0, bf1[ct][0], acc, 0, 0, 0);
        acc = __builtin_amdgcn_mfma_f32_16x16x32_bf16(a1, bf1[ct][1], acc, 0, 0, 0);
#pragma unroll
        for (int r = 0; r < 4; r++)
            my[(q * 4 + r) * 80 + ct * 16 + m] = f2bf(fmaxf(acc[r], 0.f));
    }
    short8 a20 = *(short8*)&my[m * 80 + q * 8];
    short8 a21 = *(short8*)&my[m * 80 + 32 + q * 8];
#pragma unroll
    for (int ct = 0; ct < 4; ct++) {
        float bv = b2[ct * 16 + m];
        v4f acc = {bv, bv, bv, bv};
        acc = __builtin_amdgcn_mfma_f32_16x16x32_bf16(a20, bf2[ct][0], acc, 0, 0, 0);
        acc = __builtin_amdgcn_mfma_f32_16x16x32_bf16(a21, bf2[ct][1], acc, 0, 0, 0);
#pragma unroll
        for (int r = 0; r < 4; r++)
            my[(q * 4 + r) * 80 + ct * 16 + m] = f2bf(acc[r]);
    }
#pragma unroll
    for (int i = 0; i < 2; i++) {
        int idx = i * 64 + lane;
        int r = idx >> 3, ch = (idx & 7) * 8;
        int grow = nbase + r;
        uint4 v = *(uint4*)&my[r * 80 + ch];
        if (grow < N_NODES) *(uint4*)&hout[grow * 64 + ch] = v;
    }
    float s_acc = 0.f, q_acc = 0.f;
    int cur = sG[w][0];
    for (int r = 0; r < 16; r++) {
        int g2 = sG[w][r];
        if (g2 != cur) {
            if (cur >= 0) {
                atomicAdd(&gsum[cur * 64 + lane], s_acc);
                atomicAdd(&gsq[cur * 64 + lane], q_acc);
            }
            cur = g2; s_acc = 0.f; q_acc = 0.f;
        }
        if (g2 >= 0) {
            float v = bf2f(my[r * 80 + lane]);
            s_acc += v; q_acc += v * v;
        }
    }
    if (cur >= 0) {
        atomicAdd(&gsum[cur * 64 + lane], s_acc);
        atomicAdd(&gsq[cur * 64 + lane], q_acc);
    }
}

__global__ __launch_bounds__(256) void k_apply_proj(const bfu* __restrict__ h,
                                                    const int* __restrict__ gid,
                                                    const float* __restrict__ gsum,
                                                    const float* __restrict__ gsq,
                                                    const float* __restrict__ inv_safe,
                                                    const float* __restrict__ ncnt,
                                                    const float* __restrict__ gnw, const float* __restrict__ gnb,
                                                    const float* __restrict__ gns,
                                                    const bfu* __restrict__ p1t, const float* __restrict__ pb1,
                                                    const bfu* __restrict__ p2t,
                                                    bfu* __restrict__ feat, float* __restrict__ out, int l) {
    __shared__ bfu ldsT[4][16 * 80];
    __shared__ int sG[4][16];
    int t = threadIdx.x;
    int w = t >> 6, lane = t & 63, m = lane & 15, q = lane >> 4;
    int row0 = blockIdx.x * 64;
    int nbase = row0 + w * 16;
    int row = nbase + m;
    bool valid = row < N_NODES;
    if (lane < 16) sG[w][lane] = (nbase + lane < N_NODES) ? gid[nbase + lane] : -1;

    union Pack { short8 v; bfu u[8]; uint4 qv; };
    Pack a0, a1;
    a0.qv = make_uint4(0u, 0u, 0u, 0u);
    a1.qv = make_uint4(0u, 0u, 0u, 0u);
    if (valid) {
        int g = gid[row];
        float inv = inv_safe[g];
        float nnf = ncnt[g];
#pragma unroll
        for (int kk = 0; kk < 2; kk++) {
            int ch = kk * 32 + q * 8;
            uint4 hv = *(const uint4*)&h[row * 64 + ch];
            float4 Sa = *(const float4*)&gsum[g * 64 + ch];
            float4 Sb = *(const float4*)&gsum[g * 64 + ch + 4];
            float4 Qa = *(const float4*)&gsq[g * 64 + ch];
            float4 Qb = *(const float4*)&gsq[g * 64 + ch + 4];
            float4 nsa = *(const float4*)&gns[ch];
            float4 nsb = *(const float4*)&gns[ch + 4];
            float4 nwa = *(const float4*)&gnw[ch];
            float4 nwb = *(const float4*)&gnw[ch + 4];
            float4 gba = *(const float4*)&gnb[ch];
            float4 gbb = *(const float4*)&gnb[ch + 4];
            float hval[8] = {bflo(hv.x), bfhi(hv.x), bflo(hv.y), bfhi(hv.y),
                             bflo(hv.z), bfhi(hv.z), bflo(hv.w), bfhi(hv.w)};
            float Sv[8] = {Sa.x, Sa.y, Sa.z, Sa.w, Sb.x, Sb.y, Sb.z, Sb.w};
            float Qv[8] = {Qa.x, Qa.y, Qa.z, Qa.w, Qb.x, Qb.y, Qb.z, Qb.w};
            float nsv[8] = {nsa.x, nsa.y, nsa.z, nsa.w, nsb.x, nsb.y, nsb.z, nsb.w};
            float nwv[8] = {nwa.x, nwa.y, nwa.z, nwa.w, nwb.x, nwb.y, nwb.z, nwb.w};
            float gbv[8] = {gba.x, gba.y, gba.z, gba.w, gbb.x, gbb.y, gbb.z, gbb.w};
            Pack& a = kk ? a1 : a0;
#pragma unroll
            for (int j = 0; j < 8; j++) {
                float ms = Sv[j] * inv * nsv[j];
                float var = (Qv[j] - 2.f * ms * Sv[j] + nnf * ms * ms) * inv;
                float coef = nwv[j] * rsqrtf(var + 1e-8f);
                a.u[j] = f2bf(fmaxf(coef * (hval[j] - ms) + gbv[j], 0.f));
            }
            *(uint4*)&feat[row * 64 + ch] = a.qv;
        }
    }

    short8 bf1[4][2], bf2[2][2];
#pragma unroll
    for (int ct = 0; ct < 4; ct++)
#pragma unroll
        for (int kk = 0; kk < 2; kk++)
            bf1[ct][kk] = *(const short8*)&p1t[(ct * 16 + m) * 64 + kk * 32 + q * 8];
#pragma unroll
    for (int ct = 0; ct < 2; ct++)
#pragma unroll
        for (int kk = 0; kk < 2; kk++)
            bf2[ct][kk] = *(const short8*)&p2t[(ct * 16 + m) * 64 + kk * 32 + q * 8];

    bfu* tl = ldsT[w];
#pragma unroll
    for (int ct = 0; ct < 4; ct++) {
        float bv = pb1[ct * 16 + m];
        v4f acc = {bv, bv, bv, bv};
        acc = __builtin_amdgcn_mfma_f32_16x16x32_bf16(a0.v, bf1[ct][0], acc, 0, 0, 0);
        acc = __builtin_amdgcn_mfma_f32_16x16x32_bf16(a1.v, bf1[ct][1], acc, 0, 0, 0);
#pragma unroll
        for (int r = 0; r < 4; r++)
            tl[(q * 4 + r) * 80 + ct * 16 + m] = f2bf(fmaxf(acc[r], 0.f));
    }
    short8 a20 = *(short8*)&tl[m * 80 + q * 8];
    short8 a21 = *(short8*)&tl[m * 80 + 32 + q * 8];

    v4f pz0 = {0.f, 0.f, 0.f, 0.f}, pz1 = {0.f, 0.f, 0.f, 0.f};
    pz0 = __builtin_amdgcn_mfma_f32_16x16x32_bf16(a20, bf2[0][0], pz0, 0, 0, 0);
    pz0 = __builtin_amdgcn_mfma_f32_16x16x32_bf16(a21, bf2[0][1], pz0, 0, 0, 0);
    pz1 = __builtin_amdgcn_mfma_f32_16x16x32_bf16(a20, bf2[1][0], pz1, 0, 0, 0);
    pz1 = __builtin_amdgcn_mfma_f32_16x16x32_bf16(a21, bf2[1][1], pz1, 0, 0, 0);

    int g0 = sG[w][0], g15 = sG[w][15];
    if (g0 == g15 && g0 >= 0) {
        float s0 = pz0[0] + pz0[1] + pz0[2] + pz0[3];
        float s1 = pz1[0] + pz1[1] + pz1[2] + pz1[3];
        s0 += __shfl_xor(s0, 16, 64); s0 += __shfl_xor(s0, 32, 64);
        s1 += __shfl_xor(s1, 16, 64); s1 += __shfl_xor(s1, 32, 64);
        if (q == 0) {
            float inv = inv_safe[g0];
            atomicAdd(&out[g0 * (NLAYERS * TDIM) + l * TDIM + m], s0 * inv);
            atomicAdd(&out[g0 * (NLAYERS * TDIM) + l * TDIM + 16 + m], s1 * inv);
        }
    } else {
        float r0acc = 0.f, r1acc = 0.f;
        int curg = -2;
#pragma unroll
        for (int rr = 0; rr < 16; rr++) {
            const int qq = rr >> 2, r = rr & 3;
            float v0 = (q == qq) ? pz0[r] : 0.f;
            float v1 = (q == qq) ? pz1[r] : 0.f;
            v0 += __shfl_xor(v0, 16, 64); v0 += __shfl_xor(v0, 32, 64);
            v1 += __shfl_xor(v1, 16, 64); v1 += __shfl_xor(v1, 32, 64);
            int g2 = sG[w][rr];
            if (g2 != curg) {
                if (curg >= 0 && q == 0) {
                    float inv = inv_safe[curg];
                    atomicAdd(&out[curg * (NLAYERS * TDIM) + l * TDIM + m], r0acc * inv);
                    atomicAdd(&out[curg * (NLAYERS * TDIM) + l * TDIM + 16 + m], r1acc * inv);
                }
                curg = g2; r0acc = 0.f; r1acc = 0.f;
            }
            if (g2 >= 0) { r0acc += v0; r1acc += v1; }
        }
        if (curg >= 0 && q == 0) {
            float inv = inv_safe[curg];
            atomicAdd(&out[curg * (NLAYERS * TDIM) + l * TDIM + m], r0acc * inv);
            atomicAdd(&out[curg * (NLAYERS * TDIM) + l * TDIM + 16 + m], r1acc * inv);
        }
    }
}

// ================= COOPERATIVE PATH =================
// v9: r8 structure + (a) explicit __threadfence() (agent scope: L2 wb/inv on gfx950)
// around every grid.sync() for cross-XCD visibility of plain feat stores; (b) conv-h /
// proj scratch ALIASED onto hstage (r6-verified pattern) -> LDS ~10.5KB, so only the
// VGPR bound (launch_bounds(256,7) -> <=72) governs the required 7 blocks/CU (1792>=1563).
__global__ __launch_bounds__(256, 7) void k_layers(
        bfu* __restrict__ feat, const int* __restrict__ offs,
        const int* __restrict__ csr, const float* __restrict__ eps,
        const bfu* __restrict__ w1tA, const float* __restrict__ b1A,
        const bfu* __restrict__ w2tA, const float* __restrict__ b2A,
        const int* __restrict__ gid, float* __restrict__ gsumA,
        const float* __restrict__ inv_safe, const float* __restrict__ ncnt,
        const float* __restrict__ gnwA, const float* __restrict__ gnbA,
        const float* __restrict__ gnsA,
        const bfu* __restrict__ p1tA, const float* __restrict__ pb1A,
        const bfu* __restrict__ p2tA, float* __restrict__ out) {
    cg::grid_group grid = cg::this_grid();
    __shared__ bfu hstage[64 * 80];
    __shared__ int sG[4][16];
    int t = threadIdx.x;
    int w = t >> 6, lane = t & 63, m = lane & 15, q = lane >> 4;
    int nbase = blockIdx.x * 64 + w * 16;
    int row = nbase + m;
    bool valid = row < N_NODES;
    if (lane < 16) sG[w][lane] = (nbase + lane < N_NODES) ? gid[nbase + lane] : -1;
    bfu* my = &hstage[w * 16 * 80];   // wave's own 16 rows (aliased scratch, r6-verified)

    for (int l = 0; l < NLAYERS; l++) {
        const bfu* w1t = w1tA + l * 4096;
        const bfu* w2t = w2tA + l * 4096;
        const float* b1 = b1A + l * 64;
        const float* b2 = b2A + l * 64;
        float* gsum = gsumA + (size_t)l * 2 * NGRAPH * 64;
        float* gsq  = gsum + NGRAPH * 64;

        // ---- phase A: agg (v5 loop) into hstage ----
        {
            int nl = t >> 2;
            int c  = t & 3;
            int coff = c * 16;
            int node = blockIdx.x * 64 + nl;
            float ep = 1.0f + eps[l];
            float acc[16];
#pragma unroll
            for (int j = 0; j < 16; j++) acc[j] = 0.f;
            if (node < N_NODES) {
                int e0 = offs[node], e1 = offs[node + 1];
                if (e0 < e1) {
                    int eL = e1 - 1;
                    int sa = csr[e0];
                    int sb = csr[(e0 + 1) < eL ? (e0 + 1) : eL];
                    int sc = csr[(e0 + 2) < eL ? (e0 + 2) : eL];
                    int sd = csr[(e0 + 3) < eL ? (e0 + 3) : eL];
                    for (int e = e0; e < e1; e += 4) {
                        int en = e + 4;
                        int na = csr[en < eL ? en : eL];
                        int nb = csr[(en + 1) < eL ? (en + 1) : eL];
                        int nc = csr[(en + 2) < eL ? (en + 2) : eL];
                        int nd = csr[(en + 3) < eL ? (en + 3) : eL];
                        uint4 va0 = *(const uint4*)&feat[sa * DIM + coff];
                        uint4 va1 = *(const uint4*)&feat[sa * DIM + coff + 8];
                        uint4 vb0 = *(const uint4*)&feat[sb * DIM + coff];
                        uint4 vb1 = *(const uint4*)&feat[sb * DIM + coff + 8];
                        uint4 vc0 = *(const uint4*)&feat[sc * DIM + coff];
                        uint4 vc1 = *(const uint4*)&feat[sc * DIM + coff + 8];
                        uint4 vd0 = *(const uint4*)&feat[sd * DIM + coff];
                        uint4 vd1 = *(const uint4*)&feat[sd * DIM + coff + 8];
                        if (e + 1 >= e1) { vb0 = make_uint4(0u,0u,0u,0u); vb1 = make_uint4(0u,0u,0u,0u); }
                        if (e + 2 >= e1) { vc0 = make_uint4(0u,0u,0u,0u); vc1 = make_uint4(0u,0u,0u,0u); }
                        if (e + 3 >= e1) { vd0 = make_uint4(0u,0u,0u,0u); vd1 = make_uint4(0u,0u,0u,0u); }
                        accum8(acc, va0); accum8(acc + 8, va1);
                        accum8(acc, vb0); accum8(acc + 8, vb1);
                        accum8(acc, vc0); accum8(acc + 8, vc1);
                        accum8(acc, vd0); accum8(acc + 8, vd1);
                        sa = na; sb = nb; sc = nc; sd = nd;
                    }
                }
                uint4 s0 = *(const uint4*)&feat[node * DIM + coff];
                uint4 s1 = *(const uint4*)&feat[node * DIM + coff + 8];
                acc[0] += ep * bflo(s0.x); acc[1] += ep * bfhi(s0.x);
                acc[2] += ep * bflo(s0.y); acc[3] += ep * bfhi(s0.y);
                acc[4] += ep * bflo(s0.z); acc[5] += ep * bfhi(s0.z);
                acc[6] += ep * bflo(s0.w); acc[7] += ep * bfhi(s0.w);
                acc[8]  += ep * bflo(s1.x); acc[9]  += ep * bfhi(s1.x);
                acc[10] += ep * bflo(s1.y); acc[11] += ep * bfhi(s1.y);
                acc[12] += ep * bflo(s1.z); acc[13] += ep * bfhi(s1.z);
                acc[14] += ep * bflo(s1.w); acc[15] += ep * bfhi(s1.w);
            }
            uint4 o0, o1;
            o0.x = ((unsigned int)f2bf(acc[1])  << 16) | f2bf(acc[0]);
            o0.y = ((unsigned int)f2bf(acc[3])  << 16) | f2bf(acc[2]);
            o0.z = ((unsigned int)f2bf(acc[5])  << 16) | f2bf(acc[4]);
            o0.w = ((unsigned int)f2bf(acc[7])  << 16) | f2bf(acc[6]);
            o1.x = ((unsigned int)f2bf(acc[9])  << 16) | f2bf(acc[8]);
            o1.y = ((unsigned int)f2bf(acc[11]) << 16) | f2bf(acc[10]);
            o1.z = ((unsigned int)f2bf(acc[13]) << 16) | f2bf(acc[12]);
            o1.w = ((unsigned int)f2bf(acc[15]) << 16) | f2bf(acc[14]);
            *(uint4*)&hstage[nl * 80 + coff] = o0;
            *(uint4*)&hstage[nl * 80 + coff + 8] = o1;
        }

        {
            short8 a0 = *(const short8*)&hstage[(w * 16 + m) * 80 + q * 8];
            short8 a1 = *(const short8*)&hstage[(w * 16 + m) * 80 + 32 + q * 8];

            short8 bf1[4][2], bf2[4][2];
#pragma unroll
            for (int ct = 0; ct < 4; ct++)
#pragma unroll
                for (int kk = 0; kk < 2; kk++) {
                    bf1[ct][kk] = *(const short8*)&w1t[(ct * 16 + m) * 64 + kk * 32 + q * 8];
                    bf2[ct][kk] = *(const short8*)&w2t[(ct * 16 + m) * 64 + kk * 32 + q * 8];
                }
#pragma unroll
            for (int ct = 0; ct < 4; ct++) {
                float bv = b1[ct * 16 + m];
                v4f acc = {bv, bv, bv, bv};
                acc = __builtin_amdgcn_mfma_f32_16x16x32_bf16(a0, bf1[ct][0], acc, 0, 0, 0);
                acc = __builtin_amdgcn_mfma_f32_16x16x32_bf16(a1, bf1[ct][1], acc, 0, 0, 0);
#pragma unroll
                for (int r = 0; r < 4; r++)
                    my[(q * 4 + r) * 80 + ct * 16 + m] = f2bf(fmaxf(acc[r], 0.f));
            }
            short8 a20 = *(short8*)&my[m * 80 + q * 8];
            short8 a21 = *(short8*)&my[m * 80 + 32 + q * 8];
#pragma unroll
            for (int ct = 0; ct < 4; ct++) {
                float bv = b2[ct * 16 + m];
                v4f acc = {bv, bv, bv, bv};
                acc = __builtin_amdgcn_mfma_f32_16x16x32_bf16(a20, bf2[ct][0], acc, 0, 0, 0);
                acc = __builtin_amdgcn_mfma_f32_16x16x32_bf16(a21, bf2[ct][1], acc, 0, 0, 0);
#pragma unroll
                for (int r = 0; r < 4; r++)
                    my[(q * 4 + r) * 80 + ct * 16 + m] = f2bf(acc[r]);
            }
            float s_acc = 0.f, q_acc = 0.f;
            int cur = sG[w][0];
            for (int r = 0; r < 16; r++) {
                int g2 = sG[w][r];
                if (g2 != cur) {
                    if (cur >= 0) {
                        atomicAdd(&gsum[cur * 64 + lane], s_acc);
                        atomicAdd(&gsq[cur * 64 + lane], q_acc);
                    }
                    cur = g2; s_acc = 0.f; q_acc = 0.f;
                }
                if (g2 >= 0) {
                    float v = bf2f(my[r * 80 + lane]);
                    s_acc += v; q_acc += v * v;
                }
            }
            if (cur >= 0) {
                atomicAdd(&gsum[cur * 64 + lane], s_acc);
                atomicAdd(&gsq[cur * 64 + lane], q_acc);
            }
        }

        __threadfence();      // release: write back L2 (feat not yet written this layer; stats via atomics)
        grid.sync();
        __threadfence();      // acquire: invalidate stale L1/L2 before reading remote gsum/gsq

        // ---- phase B: norm (h from aliased LDS) + proj + per-wave pooling ----
        {
            const float* gnw = gnwA + l * 64;
            const float* gnb = gnbA + l * 64;
            const float* gns = gnsA + l * 64;
            const bfu* p1t = p1tA + l * 4096;
            const float* pb1 = pb1A + l * 64;
            const bfu* p2t = p2tA + l * 2048;

            union Pack { short8 v; bfu u[8]; uint4 qv; };
            Pack a0, a1;
            a0.qv = make_uint4(0u, 0u, 0u, 0u);
            a1.qv = make_uint4(0u, 0u, 0u, 0u);
            if (valid) {
                int g = gid[row];
                float inv = inv_safe[g];
                float nnf = ncnt[g];
#pragma unroll
                for (int kk = 0; kk < 2; kk++) {
                    int ch = kk * 32 + q * 8;
                    uint4 hv = *(uint4*)&my[m * 80 + ch];   // conv h (LDS, persisted across sync)
                    float4 Sa = *(const float4*)&gsum[g * 64 + ch];
                    float4 Sb = *(const float4*)&gsum[g * 64 + ch + 4];
                    float4 Qa = *(const float4*)&gsq[g * 64 + ch];
                    float4 Qb = *(const float4*)&gsq[g * 64 + ch + 4];
                    float4 nsa = *(const float4*)&gns[ch];
                    float4 nsb = *(const float4*)&gns[ch + 4];
                    float4 nwa = *(const float4*)&gnw[ch];
                    float4 nwb = *(const float4*)&gnw[ch + 4];
                    float4 gba = *(const float4*)&gnb[ch];
                    float4 gbb = *(const float4*)&gnb[ch + 4];
                    float hval[8] = {bflo(hv.x), bfhi(hv.x), bflo(hv.y), bfhi(hv.y),
                                     bflo(hv.z), bfhi(hv.z), bflo(hv.w), bfhi(hv.w)};
                    float Sv[8] = {Sa.x, Sa.y, Sa.z, Sa.w, Sb.x, Sb.y, Sb.z, Sb.w};
                    float Qv[8] = {Qa.x, Qa.y, Qa.z, Qa.w, Qb.x, Qb.y, Qb.z, Qb.w};
                    float nsv[8] = {nsa.x, nsa.y, nsa.z, nsa.w, nsb.x, nsb.y, nsb.z, nsb.w};
                    float nwv[8] = {nwa.x, nwa.y, nwa.z, nwa.w, nwb.x, nwb.y, nwb.z, nwb.w};
                    float gbv[8] = {gba.x, gba.y, gba.z, gba.w, gbb.x, gbb.y, gbb.z, gbb.w};
                    Pack& a = kk ? a1 : a0;
#pragma unroll
                    for (int j = 0; j < 8; j++) {
                        float ms = Sv[j] * inv * nsv[j];
                        float var = (Qv[j] - 2.f * ms * Sv[j] + nnf * ms * ms) * inv;
                        float coef = nwv[j] * rsqrtf(var + 1e-8f);
                        a.u[j] = f2bf(fmaxf(coef * (hval[j] - ms) + gbv[j], 0.f));
                    }
                    if (l < NLAYERS - 1) *(uint4*)&feat[row * 64 + ch] = a.qv;
                }
            }

            short8 bf1[4][2];
#pragma unroll
            for (int ct = 0; ct < 4; ct++)
#pragma unroll
                for (int kk = 0; kk < 2; kk++)
                    bf1[ct][kk] = *(const short8*)&p1t[(ct * 16 + m) * 64 + kk * 32 + q * 8];
#pragma unroll
            for (int ct = 0; ct < 4; ct++) {
                float bv = pb1[ct * 16 + m];
                v4f acc = {bv, bv, bv, bv};
                acc = __builtin_amdgcn_mfma_f32_16x16x32_bf16(a0.v, bf1[ct][0], acc, 0, 0, 0);
                acc = __builtin_amdgcn_mfma_f32_16x16x32_bf16(a1.v, bf1[ct][1], acc, 0, 0, 0);
#pragma unroll
                for (int r = 0; r < 4; r++)
                    my[(q * 4 + r) * 80 + ct * 16 + m] = f2bf(fmaxf(acc[r], 0.f));
            }
            short8 bf2[2][2];
#pragma unroll
            for (int ct = 0; ct < 2; ct++)
#pragma unroll
                for (int kk = 0; kk < 2; kk++)
                    bf2[ct][kk] = *(const short8*)&p2t[(ct * 16 + m) * 64 + kk * 32 + q * 8];
            short8 a20 = *(short8*)&my[m * 80 + q * 8];
            short8 a21 = *(short8*)&my[m * 80 + 32 + q * 8];

            v4f pz0 = {0.f, 0.f, 0.f, 0.f}, pz1 = {0.f, 0.f, 0.f, 0.f};
            pz0 = __builtin_amdgcn_mfma_f32_16x16x32_bf16(a20, bf2[0][0], pz0, 0, 0, 0);
            pz0 = __builtin_amdgcn_mfma_f32_16x16x32_bf16(a21, bf2[0][1], pz0, 0, 0, 0);
            pz1 = __builtin_amdgcn_mfma_f32_16x16x32_bf16(a20, bf2[1][0], pz1, 0, 0, 0);
            pz1 = __builtin_amdgcn_mfma_f32_16x16x32_bf16(a21, bf2[1][1], pz1, 0, 0, 0);

            int g0 = sG[w][0], g15 = sG[w][15];
            if (g0 == g15 && g0 >= 0) {
                float s0 = pz0[0] + pz0[1] + pz0[2] + pz0[3];
                float s1 = pz1[0] + pz1[1] + pz1[2] + pz1[3];
                s0 += __shfl_xor(s0, 16, 64); s0 += __shfl_xor(s0, 32, 64);
                s1 += __shfl_xor(s1, 16, 64); s1 += __shfl_xor(s1, 32, 64);
                if (q == 0) {
                    float inv = inv_safe[g0];
                    atomicAdd(&out[g0 * (NLAYERS * TDIM) + l * TDIM + m], s0 * inv);
                    atomicAdd(&out[g0 * (NLAYERS * TDIM) + l * TDIM + 16 + m], s1 * inv);
                }
            } else {
                float r0acc = 0.f, r1acc = 0.f;
                int curg = -2;
#pragma unroll
                for (int rr = 0; rr < 16; rr++) {
                    const int qq = rr >> 2, r = rr & 3;
                    float v0 = (q == qq) ? pz0[r] : 0.f;
                    float v1 = (q == qq) ? pz1[r] : 0.f;
                    v0 += __shfl_xor(v0, 16, 64); v0 += __shfl_xor(v0, 32, 64);
                    v1 += __shfl_xor(v1, 16, 64); v1 += __shfl_xor(v1, 32, 64);
                    int g2 = sG[w][rr];
                    if (g2 != curg) {
                        if (curg >= 0 && q == 0) {
                            float inv = inv_safe[curg];
                            atomicAdd(&out[curg * (NLAYERS * TDIM) + l * TDIM + m], r0acc * inv);
                            atomicAdd(&out[curg * (NLAYERS * TDIM) + l * TDIM + 16 + m], r1acc * inv);
                        }
                        curg = g2; r0acc = 0.f; r1acc = 0.f;
                    }
                    if (g2 >= 0) { r0acc += v0; r1acc += v1; }
                }
                if (curg >= 0 && q == 0) {
                    float inv = inv_safe[curg];
                    atomicAdd(&out[curg * (NLAYERS * TDIM) + l * TDIM + m], r0acc * inv);
                    atomicAdd(&out[curg * (NLAYERS * TDIM) + l * TDIM + 16 + m], r1acc * inv);
                }
            }
        }

        if (l != NLAYERS - 1) {
            __threadfence();   // release feat stores (L2 writeback)
            grid.sync();
            __threadfence();   // acquire before next layer's remote feat gathers
        }
    }
}

// ---------------- launcher ----------------

extern "C" void kernel_launch(void* const* d_in, const int* in_sizes, int n_in,
                              void* d_out, int out_size, void* d_ws, size_t ws_size,
                              hipStream_t stream) {
    const float* x        = (const float*)d_in[0];
    const int*   src      = (const int*)d_in[1];
    const int*   dst      = (const int*)d_in[2];
    const int*   gid      = (const int*)d_in[3];
    const float* eps      = (const float*)d_in[4];
    const float* conv_w1  = (const float*)d_in[5];
    const float* conv_b1  = (const float*)d_in[6];
    const float* conv_w2  = (const float*)d_in[7];
    const float* conv_b2  = (const float*)d_in[8];
    const float* gn_w     = (const float*)d_in[9];
    const float* gn_b     = (const float*)d_in[10];
    const float* gn_s     = (const float*)d_in[11];
    const float* proj_w1  = (const float*)d_in[12];
    const float* proj_b1  = (const float*)d_in[13];
    const float* proj_w2  = (const float*)d_in[14];
    const float* proj_b2  = (const float*)d_in[15];
    float* out = (float*)d_out;

    char* ws = (char*)d_ws;
    size_t off = 0;
    auto alloc = [&](size_t bytes) { char* p = ws + off; off += (bytes + 255) & ~(size_t)255; return p; };
    int*   offs     = (int*)alloc(NP * sizeof(int));
    int*   gstart   = (int*)alloc((NGRAPH + 1) * sizeof(int));
    float* inv_safe = (float*)alloc(NGRAPH * sizeof(float));
    float* ncnt     = (float*)alloc(NGRAPH * sizeof(float));
    int*   bcnt     = (int*)alloc(NBUCK * sizeof(int));
    float* gsumA    = (float*)alloc((size_t)NLAYERS * 2 * NGRAPH * 64 * sizeof(float));
    size_t zbytes   = (size_t)((char*)(gsumA + (size_t)NLAYERS * 2 * NGRAPH * 64) - (char*)bcnt);
    int*   bbase    = (int*)alloc((NBUCK + 1) * sizeof(int));
    int*   bcursor  = (int*)alloc(NBUCK * sizeof(int));
    int*   csr      = (int*)alloc(N_EDGES * sizeof(int));
    bfu*   featbf   = (bfu*)alloc((size_t)N_NODES * DIM * sizeof(bfu));
    bfu*   hbufbf   = (bfu*)alloc((size_t)N_NODES * DIM * sizeof(bfu));   // fallback only
    bfu*   w1t      = (bfu*)alloc((size_t)NLAYERS * 4096 * sizeof(bfu));
    bfu*   w2t      = (bfu*)alloc((size_t)NLAYERS * 4096 * sizeof(bfu));
    bfu*   p1t      = (bfu*)alloc((size_t)NLAYERS * 4096 * sizeof(bfu));
    bfu*   p2t      = (bfu*)alloc((size_t)NLAYERS * 2048 * sizeof(bfu));
    int2*  ebuf     = (int2*)alloc((size_t)N_EDGES * sizeof(int2));   // setup-only

    hipMemsetAsync(bcnt, 0, zbytes, stream);
    k_setup<<<6555, 256, 0, stream>>>(x, featbf, gid, gstart, inv_safe, ncnt,
                                      conv_w1, conv_w2, proj_w1, proj_w2, w1t, w2t, p1t, p2t,
                                      dst, bcnt);
    k_bscan<<<1, 256, 0, stream>>>(bcnt, bbase, bcursor, gstart, proj_b2, out);
    k_bscatter<<<256, 256, 0, stream>>>(src, dst, bcursor, ebuf);
    k_bcsr<<<NBUCK, 256, 0, stream>>>(ebuf, bbase, offs, csr);

    // cooperative 3-layer mega-kernel; on launch failure fall back to r7 per-layer path
    void* kargs[] = {
        (void*)&featbf, (void*)&offs, (void*)&csr, (void*)&eps,
        (void*)&w1t, (void*)&conv_b1, (void*)&w2t, (void*)&conv_b2,
        (void*)&gid, (void*)&gsumA,
        (void*)&inv_safe, (void*)&ncnt,
        (void*)&gn_w, (void*)&gn_b, (void*)&gn_s,
        (void*)&p1t, (void*)&proj_b1, (void*)&p2t,
        (void*)&out
    };
    hipError_t cerr = hipLaunchCooperativeKernel((const void*)k_layers, dim3(MLPBL), dim3(256),
                                                 kargs, 0, stream);
    if (cerr != hipSuccess) {
        (void)hipGetLastError();   // clear sticky error
        for (int l = 0; l < NLAYERS; l++) {
            float* gsum_l = gsumA + (size_t)l * 2 * NGRAPH * 64;
            float* gsq_l  = gsum_l + NGRAPH * 64;
            k_mlp<<<MLPBL, 256, 0, stream>>>(featbf, offs, csr, eps, l,
                                             w1t + l * 4096, conv_b1 + l * 64,
                                             w2t + l * 4096, conv_b2 + l * 64,
                                             gid, hbufbf, gsum_l, gsq_l);
            k_apply_proj<<<MLPBL, 256, 0, stream>>>(hbufbf, gid, gsum_l, gsq_l, inv_safe, ncnt,
                                                    gn_w + l * 64, gn_b + l * 64, gn_s + l * 64,
                                                    p1t + l * 4096, proj_b1 + l * 64,
                                                    p2t + l * 2048, featbf, out, l);
        }
    }
}

// Round 10
// 364.513 us; speedup vs baseline: 7.3140x; 7.3140x over previous
//
#include <hip/hip_runtime.h>
#include <math.h>

#define N_NODES 100000
#define N_EDGES 1200000
#define DIM 64
#define TDIM 32
#define NLAYERS 3
#define NGRAPH 500
#define NP (N_NODES + 1)

#define BUCKW 512                      // nodes per bucket (dst >> 9)
#define NBUCK ((N_NODES + BUCKW - 1) / BUCKW)   // 196
#define ECHUNK ((N_EDGES + 255) / 256)          // 4688 edges per block (256 blocks)
#define MLPBL ((N_NODES + 63) / 64)             // 1563

typedef unsigned short bfu;
typedef __attribute__((ext_vector_type(8))) short short8;
typedef __attribute__((ext_vector_type(4))) float v4f;

__device__ __forceinline__ float bf2f(bfu u) {
    union { unsigned int i; float f; } v; v.i = ((unsigned int)u) << 16; return v.f;
}
__device__ __forceinline__ float bflo(unsigned int d) {
    union { unsigned int i; float f; } v; v.i = d << 16; return v.f;
}
__device__ __forceinline__ float bfhi(unsigned int d) {
    union { unsigned int i; float f; } v; v.i = d & 0xFFFF0000u; return v.f;
}
__device__ __forceinline__ bfu f2bf(float f) {
    union { float f; unsigned int i; } v; v.f = f;
    unsigned int r = v.i + 0x7FFFu + ((v.i >> 16) & 1u);   // RNE
    return (bfu)(r >> 16);
}
__device__ __forceinline__ void accum8(float* acc, uint4 d) {
    acc[0] += bflo(d.x); acc[1] += bfhi(d.x);
    acc[2] += bflo(d.y); acc[3] += bfhi(d.y);
    acc[4] += bflo(d.z); acc[5] += bfhi(d.z);
    acc[6] += bflo(d.w); acc[7] += bfhi(d.w);
}

// ---------------- merged setup ----------------
// blocks 0..6249: x->bf16 ; 6250: graph ranges/inv/ncnt ; 6251..6298: weight prep ;
// 6299..6554: bucket histogram (bcnt pre-zeroed by memset, prior dispatch)
__global__ __launch_bounds__(256) void k_setup(const float* __restrict__ x, bfu* __restrict__ xb,
                                               const int* __restrict__ gid, int* __restrict__ gstart,
                                               float* __restrict__ inv_safe, float* __restrict__ ncnt,
                                               const float* __restrict__ w1, const float* __restrict__ w2,
                                               const float* __restrict__ q1, const float* __restrict__ q2,
                                               bfu* __restrict__ w1t, bfu* __restrict__ w2t,
                                               bfu* __restrict__ q1t, bfu* __restrict__ q2t,
                                               const int* __restrict__ dst, int* __restrict__ bcnt) {
    int b = blockIdx.x, t = threadIdx.x;
    if (b < 6250) {
        int base = (b * 256 + t) * 4;
        float4 v = *(const float4*)&x[base];
        ushort4 o;
        o.x = f2bf(v.x); o.y = f2bf(v.y); o.z = f2bf(v.z); o.w = f2bf(v.w);
        *(ushort4*)&xb[base] = o;
    } else if (b == 6250) {
        for (int tt = t; tt <= NGRAPH; tt += 256) {
            int lo = 0, hi = N_NODES;
            while (lo < hi) {
                int mid = (lo + hi) >> 1;
                if (gid[mid] < tt) lo = mid + 1; else hi = mid;
            }
            gstart[tt] = lo;
        }
        __syncthreads();
        for (int tt = t; tt < NGRAPH; tt += 256) {
            int c = gstart[tt + 1] - gstart[tt];
            inv_safe[tt] = 1.0f / (float)(c > 1 ? c : 1);
            ncnt[tt] = (float)c;
        }
    } else if (b < 6299) {
        int i = (b - 6251) * 256 + t;     // 0..12287
        int l = i >> 12, k = (i >> 6) & 63, n = i & 63;
        int o = (l << 12) | (n << 6) | k;
        w1t[o] = f2bf(w1[i]);
        w2t[o] = f2bf(w2[i]);
        q1t[o] = f2bf(q1[i]);
        if (i < NLAYERS * 2048) {
            int l2 = i >> 11, rem = i & 2047, k2 = rem >> 5, n2 = rem & 31;
            q2t[l2 * 2048 + n2 * 64 + k2] = f2bf(q2[i]);
        }
    } else {
        __shared__ int h[NBUCK];
        for (int i = t; i < NBUCK; i += 256) h[i] = 0;
        __syncthreads();
        int e0 = (b - 6299) * ECHUNK;
        int e1 = e0 + ECHUNK; if (e1 > N_EDGES) e1 = N_EDGES;
        for (int e = e0 + t; e < e1; e += 256) atomicAdd(&h[dst[e] >> 9], 1);
        __syncthreads();
        for (int i = t; i < NBUCK; i += 256) if (h[i]) atomicAdd(&bcnt[i], h[i]);
    }
}

// ---------------- setup: bucket scan (+ out-bias pre-write; gstart from prior dispatch) ----------------
__global__ __launch_bounds__(256) void k_bscan(const int* __restrict__ bcnt,
                                               int* __restrict__ bbase, int* __restrict__ bcursor,
                                               const int* __restrict__ gstart,
                                               const float* __restrict__ pb2all, float* __restrict__ out) {
    __shared__ int s[256];
    int t = threadIdx.x;
    s[t] = (t < NBUCK) ? bcnt[t] : 0;
    __syncthreads();
    for (int off = 1; off < 256; off <<= 1) {
        int v = (t >= off) ? s[t - off] : 0;
        __syncthreads();
        s[t] += v;
        __syncthreads();
    }
    int ex = t ? s[t - 1] : 0;
    if (t < NBUCK) { bbase[t] = ex; bcursor[t] = ex; }
    if (t == 0) bbase[NBUCK] = N_EDGES;
    // out-bias pre-write (covers d_out poison; pooling adds atomically later)
    for (int g = t; g < NGRAPH; g += 256) {
        int nn = gstart[g + 1] - gstart[g];
        for (int r = 0; r < NLAYERS * TDIM; r++)
            out[g * (NLAYERS * TDIM) + r] = (nn > 0) ? pb2all[r] : 0.f;
    }
}

__global__ __launch_bounds__(256) void k_bscatter(const int* __restrict__ src, const int* __restrict__ dst,
                                                  int* __restrict__ bcursor, int2* __restrict__ ebuf) {
    __shared__ int cnt[NBUCK];
    __shared__ int base[NBUCK];
    int t = threadIdx.x;
    for (int i = t; i < NBUCK; i += 256) cnt[i] = 0;
    __syncthreads();
    int e0 = blockIdx.x * ECHUNK;
    int e1 = e0 + ECHUNK; if (e1 > N_EDGES) e1 = N_EDGES;
    for (int e = e0 + t; e < e1; e += 256) atomicAdd(&cnt[dst[e] >> 9], 1);
    __syncthreads();
    for (int i = t; i < NBUCK; i += 256) base[i] = cnt[i] ? atomicAdd(&bcursor[i], cnt[i]) : 0;
    __syncthreads();
    for (int i = t; i < NBUCK; i += 256) cnt[i] = 0;
    __syncthreads();
    for (int e = e0 + t; e < e1; e += 256) {
        int d = dst[e];
        int b = d >> 9;
        int r = atomicAdd(&cnt[b], 1);
        ebuf[base[b] + r] = make_int2(src[e], d);
    }
}

__global__ __launch_bounds__(256) void k_bcsr(const int2* __restrict__ ebuf, const int* __restrict__ bbase,
                                              int* __restrict__ offs, int* __restrict__ csr) {
    __shared__ int ldeg[BUCKW];
    __shared__ int lscan[BUCKW];
    __shared__ int lcur[BUCKW];
    int t = threadIdx.x;
    int b = blockIdx.x;
    int nbase = b << 9;
    int ebeg = bbase[b], eend = bbase[b + 1];
    ldeg[t] = 0; ldeg[t + 256] = 0;
    __syncthreads();
    for (int e = ebeg + t; e < eend; e += 256) atomicAdd(&ldeg[ebuf[e].y - nbase], 1);
    __syncthreads();
    lscan[t] = ldeg[t]; lscan[t + 256] = ldeg[t + 256];
    __syncthreads();
    for (int off = 1; off < BUCKW; off <<= 1) {
        int i0 = t, i1 = t + 256;
        int v0 = (i0 >= off) ? lscan[i0 - off] : 0;
        int v1 = (i1 >= off) ? lscan[i1 - off] : 0;
        __syncthreads();
        lscan[i0] += v0; lscan[i1] += v1;
        __syncthreads();
    }
    int ex0 = lscan[t] - ldeg[t];
    int ex1 = lscan[t + 256] - ldeg[t + 256];
    lcur[t] = ex0; lcur[t + 256] = ex1;
    int n0 = nbase + t, n1 = nbase + t + 256;
    if (n0 < N_NODES) offs[n0] = ebeg + ex0;
    if (n1 < N_NODES) offs[n1] = ebeg + ex1;
    if (b == 0 && t == 0) offs[N_NODES] = N_EDGES;
    __syncthreads();
    for (int e = ebeg + t; e < eend; e += 256) {
        int2 p = ebuf[e];
        int slot = atomicAdd(&lcur[p.y - nbase], 1);
        csr[ebeg + slot] = p.x;
    }
}

// ---------------- per-layer: FUSED aggregation + conv MLP (MFMA) + per-graph stats ----------------
// v10: v5 agg loop + MFMA scratch ALIASED onto hstage (pattern correctness-verified in the
// r9 cooperative run): agg writes wave w's rows [w*16,(w+1)*16); a0/a1 read them (same wave,
// in-order DS) BEFORE the conv MFMAs overwrite the same region. LDS 21KB -> 10.5KB ->
// occupancy 7 blocks/28 waves -> 8 blocks/32 waves per CU.
__global__ __launch_bounds__(256) void k_mlp(const bfu* __restrict__ feat, const int* __restrict__ offs,
                                             const int* __restrict__ csr, const float* __restrict__ eps, int l,
                                             const bfu* __restrict__ w1t, const float* __restrict__ b1,
                                             const bfu* __restrict__ w2t, const float* __restrict__ b2,
                                             const int* __restrict__ gid, bfu* __restrict__ hout,
                                             float* __restrict__ gsum, float* __restrict__ gsq) {
    __shared__ bfu hstage[64 * 80];
    __shared__ int sG[4][16];
    int t = threadIdx.x;
    int w = t >> 6, lane = t & 63, m = lane & 15, q = lane >> 4;
    int nbase = blockIdx.x * 64 + w * 16;
    if (lane < 16) sG[w][lane] = (nbase + lane < N_NODES) ? gid[nbase + lane] : -1;

    // ---- agg phase: 64 nodes in one parallel pass (v5: unroll-4 + pipelined indices) ----
    {
        int nl = t >> 2;                 // node-local 0..63
        int c  = t & 3;                  // channel quarter
        int coff = c * 16;
        int node = blockIdx.x * 64 + nl;
        float ep = 1.0f + eps[l];
        float acc[16];
#pragma unroll
        for (int j = 0; j < 16; j++) acc[j] = 0.f;
        if (node < N_NODES) {
            int e0 = offs[node], e1 = offs[node + 1];
            if (e0 < e1) {
                int eL = e1 - 1;
                int sa = csr[e0];
                int sb = csr[(e0 + 1) < eL ? (e0 + 1) : eL];
                int sc = csr[(e0 + 2) < eL ? (e0 + 2) : eL];
                int sd = csr[(e0 + 3) < eL ? (e0 + 3) : eL];
                for (int e = e0; e < e1; e += 4) {
                    int en = e + 4;
                    int na = csr[en < eL ? en : eL];
                    int nb = csr[(en + 1) < eL ? (en + 1) : eL];
                    int nc = csr[(en + 2) < eL ? (en + 2) : eL];
                    int nd = csr[(en + 3) < eL ? (en + 3) : eL];
                    uint4 va0 = *(const uint4*)&feat[sa * DIM + coff];
                    uint4 va1 = *(const uint4*)&feat[sa * DIM + coff + 8];
                    uint4 vb0 = *(const uint4*)&feat[sb * DIM + coff];
                    uint4 vb1 = *(const uint4*)&feat[sb * DIM + coff + 8];
                    uint4 vc0 = *(const uint4*)&feat[sc * DIM + coff];
                    uint4 vc1 = *(const uint4*)&feat[sc * DIM + coff + 8];
                    uint4 vd0 = *(const uint4*)&feat[sd * DIM + coff];
                    uint4 vd1 = *(const uint4*)&feat[sd * DIM + coff + 8];
                    if (e + 1 >= e1) { vb0 = make_uint4(0u,0u,0u,0u); vb1 = make_uint4(0u,0u,0u,0u); }
                    if (e + 2 >= e1) { vc0 = make_uint4(0u,0u,0u,0u); vc1 = make_uint4(0u,0u,0u,0u); }
                    if (e + 3 >= e1) { vd0 = make_uint4(0u,0u,0u,0u); vd1 = make_uint4(0u,0u,0u,0u); }
                    accum8(acc, va0); accum8(acc + 8, va1);
                    accum8(acc, vb0); accum8(acc + 8, vb1);
                    accum8(acc, vc0); accum8(acc + 8, vc1);
                    accum8(acc, vd0); accum8(acc + 8, vd1);
                    sa = na; sb = nb; sc = nc; sd = nd;
                }
            }
            uint4 s0 = *(const uint4*)&feat[node * DIM + coff];
            uint4 s1 = *(const uint4*)&feat[node * DIM + coff + 8];
            acc[0] += ep * bflo(s0.x); acc[1] += ep * bfhi(s0.x);
            acc[2] += ep * bflo(s0.y); acc[3] += ep * bfhi(s0.y);
            acc[4] += ep * bflo(s0.z); acc[5] += ep * bfhi(s0.z);
            acc[6] += ep * bflo(s0.w); acc[7] += ep * bfhi(s0.w);
            acc[8]  += ep * bflo(s1.x); acc[9]  += ep * bfhi(s1.x);
            acc[10] += ep * bflo(s1.y); acc[11] += ep * bfhi(s1.y);
            acc[12] += ep * bflo(s1.z); acc[13] += ep * bfhi(s1.z);
            acc[14] += ep * bflo(s1.w); acc[15] += ep * bfhi(s1.w);
        }
        uint4 o0, o1;
        o0.x = ((unsigned int)f2bf(acc[1])  << 16) | f2bf(acc[0]);
        o0.y = ((unsigned int)f2bf(acc[3])  << 16) | f2bf(acc[2]);
        o0.z = ((unsigned int)f2bf(acc[5])  << 16) | f2bf(acc[4]);
        o0.w = ((unsigned int)f2bf(acc[7])  << 16) | f2bf(acc[6]);
        o1.x = ((unsigned int)f2bf(acc[9])  << 16) | f2bf(acc[8]);
        o1.y = ((unsigned int)f2bf(acc[11]) << 16) | f2bf(acc[10]);
        o1.z = ((unsigned int)f2bf(acc[13]) << 16) | f2bf(acc[12]);
        o1.w = ((unsigned int)f2bf(acc[15]) << 16) | f2bf(acc[14]);
        *(uint4*)&hstage[nl * 80 + coff] = o0;
        *(uint4*)&hstage[nl * 80 + coff + 8] = o1;
    }
    // Same-wave LDS dependency (lgkmcnt) — no barrier needed.

    short8 a0 = *(const short8*)&hstage[(w * 16 + m) * 80 + q * 8];
    short8 a1 = *(const short8*)&hstage[(w * 16 + m) * 80 + 32 + q * 8];

    short8 bf1[4][2], bf2[4][2];
#pragma unroll
    for (int ct = 0; ct < 4; ct++)
#pragma unroll
        for (int kk = 0; kk < 2; kk++) {
            bf1[ct][kk] = *(const short8*)&w1t[(ct * 16 + m) * 64 + kk * 32 + q * 8];
            bf2[ct][kk] = *(const short8*)&w2t[(ct * 16 + m) * 64 + kk * 32 + q * 8];
        }

    // MFMA scratch aliased onto this wave's hstage rows (a0/a1 already in registers)
    bfu* my = &hstage[w * 16 * 80];
#pragma unroll
    for (int ct = 0; ct < 4; ct++) {
        float bv = b1[ct * 16 + m];
        v4f acc = {bv, bv, bv, bv};
        acc = __builtin_amdgcn_mfma_f32_16x16x32_bf16(a0, bf1[ct][0], acc, 0, 0, 0);
        acc = __builtin_amdgcn_mfma_f32_16x16x32_bf16(a1, bf1[ct][1], acc, 0, 0, 0);
#pragma unroll
        for (int r = 0; r < 4; r++)
            my[(q * 4 + r) * 80 + ct * 16 + m] = f2bf(fmaxf(acc[r], 0.f));
    }
    short8 a20 = *(short8*)&my[m * 80 + q * 8];
    short8 a21 = *(short8*)&my[m * 80 + 32 + q * 8];
#pragma unroll
    for (int ct = 0; ct < 4; ct++) {
        float bv = b2[ct * 16 + m];
        v4f acc = {bv, bv, bv, bv};
        acc = __builtin_amdgcn_mfma_f32_16x16x32_bf16(a20, bf2[ct][0], acc, 0, 0, 0);
        acc = __builtin_amdgcn_mfma_f32_16x16x32_bf16(a21, bf2[ct][1], acc, 0, 0, 0);
#pragma unroll
        for (int r = 0; r < 4; r++)
            my[(q * 4 + r) * 80 + ct * 16 + m] = f2bf(acc[r]);
    }
#pragma unroll
    for (int i = 0; i < 2; i++) {
        int idx = i * 64 + lane;
        int r = idx >> 3, ch = (idx & 7) * 8;
        int grow = nbase + r;
        uint4 v = *(uint4*)&my[r * 80 + ch];
        if (grow < N_NODES) *(uint4*)&hout[grow * 64 + ch] = v;
    }
    // per-graph stats accumulation (lane = column; ~2 packed atomics/wave)
    float s_acc = 0.f, q_acc = 0.f;
    int cur = sG[w][0];
    for (int r = 0; r < 16; r++) {
        int g2 = sG[w][r];
        if (g2 != cur) {
            if (cur >= 0) {
                atomicAdd(&gsum[cur * 64 + lane], s_acc);
                atomicAdd(&gsq[cur * 64 + lane], q_acc);
            }
            cur = g2; s_acc = 0.f; q_acc = 0.f;
        }
        if (g2 >= 0) {
            float v = bf2f(my[r * 80 + lane]);
            s_acc += v; q_acc += v * v;
        }
    }
    if (cur >= 0) {
        atomicAdd(&gsum[cur * 64 + lane], s_acc);
        atomicAdd(&gsq[cur * 64 + lane], q_acc);
    }
}

// ---------------- per-layer: inline stats finalize + norm+relu + proj MLP + pooling ----------------
// v7 per-wave in-register pooling; v10: skip the feat store on the last layer (never read).
__global__ __launch_bounds__(256) void k_apply_proj(const bfu* __restrict__ h,
                                                    const int* __restrict__ gid,
                                                    const float* __restrict__ gsum,
                                                    const float* __restrict__ gsq,
                                                    const float* __restrict__ inv_safe,
                                                    const float* __restrict__ ncnt,
                                                    const float* __restrict__ gnw, const float* __restrict__ gnb,
                                                    const float* __restrict__ gns,
                                                    const bfu* __restrict__ p1t, const float* __restrict__ pb1,
                                                    const bfu* __restrict__ p2t,
                                                    bfu* __restrict__ feat, float* __restrict__ out, int l) {
    __shared__ bfu ldsT[4][16 * 80];
    __shared__ int sG[4][16];
    int t = threadIdx.x;
    int w = t >> 6, lane = t & 63, m = lane & 15, q = lane >> 4;
    int row0 = blockIdx.x * 64;
    int nbase = row0 + w * 16;
    int row = nbase + m;
    bool valid = row < N_NODES;
    if (lane < 16) sG[w][lane] = (nbase + lane < N_NODES) ? gid[nbase + lane] : -1;

    union Pack { short8 v; bfu u[8]; uint4 qv; };
    Pack a0, a1;
    a0.qv = make_uint4(0u, 0u, 0u, 0u);
    a1.qv = make_uint4(0u, 0u, 0u, 0u);
    if (valid) {
        int g = gid[row];
        float inv = inv_safe[g];
        float nnf = ncnt[g];
#pragma unroll
        for (int kk = 0; kk < 2; kk++) {
            int ch = kk * 32 + q * 8;
            uint4 hv = *(const uint4*)&h[row * 64 + ch];
            float4 Sa = *(const float4*)&gsum[g * 64 + ch];
            float4 Sb = *(const float4*)&gsum[g * 64 + ch + 4];
            float4 Qa = *(const float4*)&gsq[g * 64 + ch];
            float4 Qb = *(const float4*)&gsq[g * 64 + ch + 4];
            float4 nsa = *(const float4*)&gns[ch];
            float4 nsb = *(const float4*)&gns[ch + 4];
            float4 nwa = *(const float4*)&gnw[ch];
            float4 nwb = *(const float4*)&gnw[ch + 4];
            float4 gba = *(const float4*)&gnb[ch];
            float4 gbb = *(const float4*)&gnb[ch + 4];
            float hval[8] = {bflo(hv.x), bfhi(hv.x), bflo(hv.y), bfhi(hv.y),
                             bflo(hv.z), bfhi(hv.z), bflo(hv.w), bfhi(hv.w)};
            float Sv[8] = {Sa.x, Sa.y, Sa.z, Sa.w, Sb.x, Sb.y, Sb.z, Sb.w};
            float Qv[8] = {Qa.x, Qa.y, Qa.z, Qa.w, Qb.x, Qb.y, Qb.z, Qb.w};
            float nsv[8] = {nsa.x, nsa.y, nsa.z, nsa.w, nsb.x, nsb.y, nsb.z, nsb.w};
            float nwv[8] = {nwa.x, nwa.y, nwa.z, nwa.w, nwb.x, nwb.y, nwb.z, nwb.w};
            float gbv[8] = {gba.x, gba.y, gba.z, gba.w, gbb.x, gbb.y, gbb.z, gbb.w};
            Pack& a = kk ? a1 : a0;
#pragma unroll
            for (int j = 0; j < 8; j++) {
                float ms = Sv[j] * inv * nsv[j];
                float var = (Qv[j] - 2.f * ms * Sv[j] + nnf * ms * ms) * inv;
                float coef = nwv[j] * rsqrtf(var + 1e-8f);
                a.u[j] = f2bf(fmaxf(coef * (hval[j] - ms) + gbv[j], 0.f));
            }
            if (l < NLAYERS - 1) *(uint4*)&feat[row * 64 + ch] = a.qv;
        }
    }

    short8 bf1[4][2], bf2[2][2];
#pragma unroll
    for (int ct = 0; ct < 4; ct++)
#pragma unroll
        for (int kk = 0; kk < 2; kk++)
            bf1[ct][kk] = *(const short8*)&p1t[(ct * 16 + m) * 64 + kk * 32 + q * 8];
#pragma unroll
    for (int ct = 0; ct < 2; ct++)
#pragma unroll
        for (int kk = 0; kk < 2; kk++)
            bf2[ct][kk] = *(const short8*)&p2t[(ct * 16 + m) * 64 + kk * 32 + q * 8];

    bfu* tl = ldsT[w];
#pragma unroll
    for (int ct = 0; ct < 4; ct++) {
        float bv = pb1[ct * 16 + m];
        v4f acc = {bv, bv, bv, bv};
        acc = __builtin_amdgcn_mfma_f32_16x16x32_bf16(a0.v, bf1[ct][0], acc, 0, 0, 0);
        acc = __builtin_amdgcn_mfma_f32_16x16x32_bf16(a1.v, bf1[ct][1], acc, 0, 0, 0);
#pragma unroll
        for (int r = 0; r < 4; r++)
            tl[(q * 4 + r) * 80 + ct * 16 + m] = f2bf(fmaxf(acc[r], 0.f));
    }
    short8 a20 = *(short8*)&tl[m * 80 + q * 8];
    short8 a21 = *(short8*)&tl[m * 80 + 32 + q * 8];

    // proj layer 2 — keep Z in registers (pb2 bias pre-written by k_bscan)
    v4f pz0 = {0.f, 0.f, 0.f, 0.f}, pz1 = {0.f, 0.f, 0.f, 0.f};
    pz0 = __builtin_amdgcn_mfma_f32_16x16x32_bf16(a20, bf2[0][0], pz0, 0, 0, 0);
    pz0 = __builtin_amdgcn_mfma_f32_16x16x32_bf16(a21, bf2[0][1], pz0, 0, 0, 0);
    pz1 = __builtin_amdgcn_mfma_f32_16x16x32_bf16(a20, bf2[1][0], pz1, 0, 0, 0);
    pz1 = __builtin_amdgcn_mfma_f32_16x16x32_bf16(a21, bf2[1][1], pz1, 0, 0, 0);

    // ---- per-wave pooling (no barrier; wave's own 16 rows) ----
    int g0 = sG[w][0], g15 = sG[w][15];
    if (g0 == g15 && g0 >= 0) {
        float s0 = pz0[0] + pz0[1] + pz0[2] + pz0[3];
        float s1 = pz1[0] + pz1[1] + pz1[2] + pz1[3];
        s0 += __shfl_xor(s0, 16, 64); s0 += __shfl_xor(s0, 32, 64);
        s1 += __shfl_xor(s1, 16, 64); s1 += __shfl_xor(s1, 32, 64);
        if (q == 0) {
            float inv = inv_safe[g0];
            atomicAdd(&out[g0 * (NLAYERS * TDIM) + l * TDIM + m], s0 * inv);
            atomicAdd(&out[g0 * (NLAYERS * TDIM) + l * TDIM + 16 + m], s1 * inv);
        }
    } else {
        float r0acc = 0.f, r1acc = 0.f;
        int curg = -2;
#pragma unroll
        for (int rr = 0; rr < 16; rr++) {
            const int qq = rr >> 2, r = rr & 3;
            float v0 = (q == qq) ? pz0[r] : 0.f;
            float v1 = (q == qq) ? pz1[r] : 0.f;
            v0 += __shfl_xor(v0, 16, 64); v0 += __shfl_xor(v0, 32, 64);
            v1 += __shfl_xor(v1, 16, 64); v1 += __shfl_xor(v1, 32, 64);
            int g2 = sG[w][rr];
            if (g2 != curg) {
                if (curg >= 0 && q == 0) {
                    float inv = inv_safe[curg];
                    atomicAdd(&out[curg * (NLAYERS * TDIM) + l * TDIM + m], r0acc * inv);
                    atomicAdd(&out[curg * (NLAYERS * TDIM) + l * TDIM + 16 + m], r1acc * inv);
                }
                curg = g2; r0acc = 0.f; r1acc = 0.f;
            }
            if (g2 >= 0) { r0acc += v0; r1acc += v1; }
        }
        if (curg >= 0 && q == 0) {
            float inv = inv_safe[curg];
            atomicAdd(&out[curg * (NLAYERS * TDIM) + l * TDIM + m], r0acc * inv);
            atomicAdd(&out[curg * (NLAYERS * TDIM) + l * TDIM + 16 + m], r1acc * inv);
        }
    }
}

// ---------------- launcher ----------------

extern "C" void kernel_launch(void* const* d_in, const int* in_sizes, int n_in,
                              void* d_out, int out_size, void* d_ws, size_t ws_size,
                              hipStream_t stream) {
    const float* x        = (const float*)d_in[0];
    const int*   src      = (const int*)d_in[1];
    const int*   dst      = (const int*)d_in[2];
    const int*   gid      = (const int*)d_in[3];
    const float* eps      = (const float*)d_in[4];
    const float* conv_w1  = (const float*)d_in[5];
    const float* conv_b1  = (const float*)d_in[6];
    const float* conv_w2  = (const float*)d_in[7];
    const float* conv_b2  = (const float*)d_in[8];
    const float* gn_w     = (const float*)d_in[9];
    const float* gn_b     = (const float*)d_in[10];
    const float* gn_s     = (const float*)d_in[11];
    const float* proj_w1  = (const float*)d_in[12];
    const float* proj_b1  = (const float*)d_in[13];
    const float* proj_w2  = (const float*)d_in[14];
    const float* proj_b2  = (const float*)d_in[15];
    float* out = (float*)d_out;

    char* ws = (char*)d_ws;
    size_t off = 0;
    auto alloc = [&](size_t bytes) { char* p = ws + off; off += (bytes + 255) & ~(size_t)255; return p; };
    int*   offs     = (int*)alloc(NP * sizeof(int));
    int*   gstart   = (int*)alloc((NGRAPH + 1) * sizeof(int));
    float* inv_safe = (float*)alloc(NGRAPH * sizeof(float));
    float* ncnt     = (float*)alloc(NGRAPH * sizeof(float));
    // zeroed region: bcnt .. gsumA (one memset covers all, padding included)
    int*   bcnt     = (int*)alloc(NBUCK * sizeof(int));
    float* gsumA    = (float*)alloc((size_t)NLAYERS * 2 * NGRAPH * 64 * sizeof(float));
    size_t zbytes   = (size_t)((char*)(gsumA + (size_t)NLAYERS * 2 * NGRAPH * 64) - (char*)bcnt);
    int*   bbase    = (int*)alloc((NBUCK + 1) * sizeof(int));
    int*   bcursor  = (int*)alloc(NBUCK * sizeof(int));
    int*   csr      = (int*)alloc(N_EDGES * sizeof(int));
    bfu*   featbf   = (bfu*)alloc((size_t)N_NODES * DIM * sizeof(bfu));
    bfu*   hbufbf   = (bfu*)alloc((size_t)N_NODES * DIM * sizeof(bfu));
    bfu*   w1t      = (bfu*)alloc((size_t)NLAYERS * 4096 * sizeof(bfu));
    bfu*   w2t      = (bfu*)alloc((size_t)NLAYERS * 4096 * sizeof(bfu));
    bfu*   p1t      = (bfu*)alloc((size_t)NLAYERS * 4096 * sizeof(bfu));
    bfu*   p2t      = (bfu*)alloc((size_t)NLAYERS * 2048 * sizeof(bfu));
    int2*  ebuf     = (int2*)alloc((size_t)N_EDGES * sizeof(int2));   // setup-only

    // setup (5 dispatches incl. memset)
    hipMemsetAsync(bcnt, 0, zbytes, stream);
    k_setup<<<6555, 256, 0, stream>>>(x, featbf, gid, gstart, inv_safe, ncnt,
                                      conv_w1, conv_w2, proj_w1, proj_w2, w1t, w2t, p1t, p2t,
                                      dst, bcnt);
    k_bscan<<<1, 256, 0, stream>>>(bcnt, bbase, bcursor, gstart, proj_b2, out);
    k_bscatter<<<256, 256, 0, stream>>>(src, dst, bcursor, ebuf);
    k_bcsr<<<NBUCK, 256, 0, stream>>>(ebuf, bbase, offs, csr);

    for (int l = 0; l < NLAYERS; l++) {
        float* gsum_l = gsumA + (size_t)l * 2 * NGRAPH * 64;
        float* gsq_l  = gsum_l + NGRAPH * 64;
        k_mlp<<<MLPBL, 256, 0, stream>>>(featbf, offs, csr, eps, l,
                                         w1t + l * 4096, conv_b1 + l * 64,
                                         w2t + l * 4096, conv_b2 + l * 64,
                                         gid, hbufbf, gsum_l, gsq_l);
        k_apply_proj<<<MLPBL, 256, 0, stream>>>(hbufbf, gid, gsum_l, gsq_l, inv_safe, ncnt,
                                                gn_w + l * 64, gn_b + l * 64, gn_s + l * 64,
                                                p1t + l * 4096, proj_b1 + l * 64,
                                                p2t + l * 2048, featbf, out, l);
    }
}